// Round 1
// baseline (642.397 us; speedup 1.0000x reference)
//
#include <hip/hip_runtime.h>

#define NN 8192
#define DD 64
#define NE 262144

// ---------------- prep: sk = normalize_rows(state_K) ----------------
// one wave (64 lanes) per row of D=64
__global__ __launch_bounds__(256) void k_prep_sk(const float* __restrict__ K,
                                                 float* __restrict__ sk) {
    int gid = blockIdx.x * blockDim.x + threadIdx.x;
    int row = gid >> 6, lane = gid & 63;
    float v = K[row * DD + lane];
    float ss = v * v;
    #pragma unroll
    for (int off = 32; off; off >>= 1) ss += __shfl_xor(ss, off, 64);
    sk[row * DD + lane] = v / sqrtf(ss);
}

// ---------------- prep: g = tanh(H), fH = -H, fK_acc = 0 ----------------
__global__ __launch_bounds__(256) void k_prep_vec(const float* __restrict__ H,
                                                  float* __restrict__ g,
                                                  float* __restrict__ fH,
                                                  float* __restrict__ fK) {
    int t = blockIdx.x * blockDim.x + threadIdx.x;
    fK[t] = 0.f;                        // zero N*D accumulator (ws is poisoned)
    if (t < NN) {
        float h = H[t];
        g[t]  = tanhf(h);
        fH[t] = -h;
    }
}

// ---------------- fH += 0.5*(W@g + W^T@g), single pass over W ----------------
#define MV_THREADS 512
#define MV_ROWS    32
__global__ __launch_bounds__(MV_THREADS) void k_matvec(const float* __restrict__ W,
                                                       const float* __restrict__ gg,
                                                       float* __restrict__ fH) {
    __shared__ float gsh[NN];       // 32 KB
    __shared__ float colacc[NN];    // 32 KB: per-block partial of W^T@g
    __shared__ float red[MV_THREADS / 64];
    for (int t = threadIdx.x; t < NN; t += MV_THREADS) {
        gsh[t]    = gg[t];
        colacc[t] = 0.f;
    }
    __syncthreads();
    const int r0 = blockIdx.x * MV_ROWS;
    for (int rl = 0; rl < MV_ROWS; ++rl) {
        const int r = r0 + rl;
        const float* __restrict__ Wr = W + (size_t)r * NN;
        const float gr = gsh[r];
        float acc = 0.f;
        #pragma unroll
        for (int it = 0; it < NN / MV_THREADS; ++it) {
            int c = it * MV_THREADS + threadIdx.x;
            float w = Wr[c];              // coalesced stream of W row
            acc += w * gsh[c];            // direct part
            colacc[c] += w * gr;          // transpose part (thread owns c: no race)
        }
        #pragma unroll
        for (int off = 32; off; off >>= 1) acc += __shfl_xor(acc, off, 64);
        if ((threadIdx.x & 63) == 0) red[threadIdx.x >> 6] = acc;
        __syncthreads();
        if (threadIdx.x == 0) {
            float s = 0.f;
            #pragma unroll
            for (int w = 0; w < MV_THREADS / 64; ++w) s += red[w];
            atomicAdd(&fH[r], 0.5f * s);
        }
        __syncthreads();
    }
    for (int t = threadIdx.x; t < NN; t += MV_THREADS)
        atomicAdd(&fH[t], 0.5f * colacc[t]);
}

// ---------------- HK edges: Gram coupling into fH and fK ----------------
// one wave per edge
__global__ __launch_bounds__(256) void k_edges_hk(const float* __restrict__ W,
                                                  const float* __restrict__ sk,
                                                  const float* __restrict__ g,
                                                  const int* __restrict__ ind,
                                                  const float* __restrict__ kH,
                                                  const float* __restrict__ kK,
                                                  float* __restrict__ fH,
                                                  float* __restrict__ fK) {
    int gid  = blockIdx.x * blockDim.x + threadIdx.x;
    int e    = gid >> 6, lane = gid & 63;
    int i = ind[2 * e], j = ind[2 * e + 1];
    float ski = sk[i * DD + lane], skj = sk[j * DD + lane];
    float d = ski * skj;
    #pragma unroll
    for (int off = 32; off; off >>= 1) d += __shfl_xor(d, off, 64);   // Gram
    float Wij = 0.5f * (W[(size_t)i * NN + j] + W[(size_t)j * NN + i]);
    float gi = g[i], gj = g[j];
    if (lane == 0) {
        float invKH = 1.f / kH[0];
        atomicAdd(&fH[i], d * Wij * gj * invKH);
        atomicAdd(&fH[j], d * Wij * gi * invKH);
    }
    float c = -gi * gj * Wij / kK[0];
    atomicAdd(&fK[i * DD + lane], c * skj);
    atomicAdd(&fK[j * DD + lane], c * ski);
}

// ---------------- K edges: polynomial interaction into fK ----------------
__global__ __launch_bounds__(256) void k_edges_k(const float* __restrict__ sk,
                                                 const int* __restrict__ ind,
                                                 const float* __restrict__ coeffs,
                                                 float* __restrict__ fK) {
    int gid  = blockIdx.x * blockDim.x + threadIdx.x;
    int e    = gid >> 6, lane = gid & 63;
    int a = ind[2 * e], b = ind[2 * e + 1];
    float ska = sk[a * DD + lane], skb = sk[b * DD + lane];
    float s = ska * skb;
    #pragma unroll
    for (int off = 32; off; off >>= 1) s += __shfl_xor(s, off, 64);
    float c0 = coeffs[0], c1 = coeffs[1], c2 = coeffs[2], c3 = coeffs[3];
    float dE = s * (c0 + s * (c1 + s * (c2 + s * c3)));   // c0 s + c1 s^2 + c2 s^3 + c3 s^4
    atomicAdd(&fK[a * DD + lane], dE * skb);
    atomicAdd(&fK[b * DD + lane], dE * ska);
}

// ---------------- finalize: fK_out = -f + sk*(sk.f) + sk @ (omega-omega^T)/2 ----------------
__global__ __launch_bounds__(256) void k_finalize(const float* __restrict__ sk,
                                                  const float* __restrict__ fk,
                                                  const float* __restrict__ omega,
                                                  float* __restrict__ outK) {
    __shared__ float A[DD * DD];    // antisymmetric part, 16 KB
    for (int t = threadIdx.x; t < DD * DD; t += 256) {
        int k = t >> 6, dcol = t & 63;
        A[t] = 0.5f * (omega[k * DD + dcol] - omega[dcol * DD + k]);
    }
    __syncthreads();
    int gid = blockIdx.x * blockDim.x + threadIdx.x;
    int row = gid >> 6, lane = gid & 63;
    float f = fk[row * DD + lane];
    float s = sk[row * DD + lane];
    float d = s * f;
    #pragma unroll
    for (int off = 32; off; off >>= 1) d += __shfl_xor(d, off, 64);   // sk . f
    float acc = 0.f;
    #pragma unroll
    for (int k = 0; k < DD; ++k) {
        float skk = __shfl(s, k, 64);
        acc += skk * A[k * DD + lane];
    }
    outK[row * DD + lane] = -f + s * d + acc;
}

extern "C" void kernel_launch(void* const* d_in, const int* in_sizes, int n_in,
                              void* d_out, int out_size, void* d_ws, size_t ws_size,
                              hipStream_t stream) {
    const float* H      = (const float*)d_in[0];
    const float* K      = (const float*)d_in[1];
    const float* W      = (const float*)d_in[2];
    const float* coeffs = (const float*)d_in[3];
    const float* omega  = (const float*)d_in[4];
    const int*   indK   = (const int*)d_in[5];
    const int*   indHK  = (const int*)d_in[6];
    const float* kK     = (const float*)d_in[7];
    const float* kH     = (const float*)d_in[8];

    float* fH    = (float*)d_out;            // N
    float* fKout = (float*)d_out + NN;       // N*D

    float* sk = (float*)d_ws;                // N*D
    float* g  = sk + (size_t)NN * DD;        // N
    float* fk = g + NN;                      // N*D accumulator

    hipLaunchKernelGGL(k_prep_sk,  dim3(NN * DD / 256), dim3(256), 0, stream, K, sk);
    hipLaunchKernelGGL(k_prep_vec, dim3(NN * DD / 256), dim3(256), 0, stream, H, g, fH, fk);
    hipLaunchKernelGGL(k_matvec,   dim3(NN / MV_ROWS),  dim3(MV_THREADS), 0, stream, W, g, fH);
    hipLaunchKernelGGL(k_edges_hk, dim3(NE / 4), dim3(256), 0, stream, W, sk, g, indHK, kH, kK, fH, fk);
    hipLaunchKernelGGL(k_edges_k,  dim3(NE / 4), dim3(256), 0, stream, sk, indK, coeffs, fk);
    hipLaunchKernelGGL(k_finalize, dim3(NN / 4), dim3(256), 0, stream, sk, fk, omega, fKout);
}

// Round 2
// 594.531 us; speedup vs baseline: 1.0805x; 1.0805x over previous
//
#include <hip/hip_runtime.h>

#define NN 8192
#define DD 64
#define NE 262144
#define CAP 256   // per-node adjacency capacity; mean deg 128, sigma 11.3 -> 256 is ~11 sigma

// ---------------- prep: sk = normalize_rows(state_K) ----------------
__global__ __launch_bounds__(256) void k_prep_sk(const float* __restrict__ K,
                                                 float* __restrict__ sk) {
    int gid = blockIdx.x * blockDim.x + threadIdx.x;
    int row = gid >> 6, lane = gid & 63;
    float v = K[row * DD + lane];
    float ss = v * v;
    #pragma unroll
    for (int off = 32; off; off >>= 1) ss += __shfl_xor(ss, off, 64);
    sk[row * DD + lane] = v / sqrtf(ss);
}

// ---------------- prep: g = tanh(H), fH = -H, cnt = 0 ----------------
__global__ __launch_bounds__(256) void k_prep_vec(const float* __restrict__ H,
                                                  float* __restrict__ g,
                                                  float* __restrict__ fH,
                                                  int* __restrict__ cnt) {
    int t = blockIdx.x * blockDim.x + threadIdx.x;   // t in [0, NN)
    float h = H[t];
    g[t]   = tanhf(h);
    fH[t]  = -h;
    cnt[t] = 0;
}

// ---------------- fH += 0.5*(W@g + W^T@g), single pass over W ----------------
#define MV_THREADS 512
#define MV_ROWS    32
__global__ __launch_bounds__(MV_THREADS) void k_matvec(const float* __restrict__ W,
                                                       const float* __restrict__ gg,
                                                       float* __restrict__ fH) {
    __shared__ float gsh[NN];       // 32 KB
    __shared__ float colacc[NN];    // 32 KB: per-block partial of W^T@g
    __shared__ float red[MV_THREADS / 64];
    for (int t = threadIdx.x; t < NN; t += MV_THREADS) {
        gsh[t]    = gg[t];
        colacc[t] = 0.f;
    }
    __syncthreads();
    const int r0 = blockIdx.x * MV_ROWS;
    for (int rl = 0; rl < MV_ROWS; ++rl) {
        const int r = r0 + rl;
        const float* __restrict__ Wr = W + (size_t)r * NN;
        const float gr = gsh[r];
        float acc = 0.f;
        #pragma unroll
        for (int it = 0; it < NN / MV_THREADS; ++it) {
            int c = it * MV_THREADS + threadIdx.x;
            float w = Wr[c];              // coalesced stream of W row
            acc += w * gsh[c];            // direct part
            colacc[c] += w * gr;          // transpose part (thread owns c: no race)
        }
        #pragma unroll
        for (int off = 32; off; off >>= 1) acc += __shfl_xor(acc, off, 64);
        if ((threadIdx.x & 63) == 0) red[threadIdx.x >> 6] = acc;
        __syncthreads();
        if (threadIdx.x == 0) {
            float s = 0.f;
            #pragma unroll
            for (int w = 0; w < MV_THREADS / 64; ++w) s += red[w];
            atomicAdd(&fH[r], 0.5f * s);
        }
        __syncthreads();
    }
    for (int t = threadIdx.x; t < NN; t += MV_THREADS)
        atomicAdd(&fH[t], 0.5f * colacc[t]);
}

// ---------------- HK edges: fH scalar scatter + adjacency build ----------------
// one wave per edge
__global__ __launch_bounds__(256) void k_edges_hk(const float* __restrict__ W,
                                                  const float* __restrict__ sk,
                                                  const float* __restrict__ g,
                                                  const int* __restrict__ ind,
                                                  const float* __restrict__ kH,
                                                  const float* __restrict__ kK,
                                                  float* __restrict__ fH,
                                                  int* __restrict__ cnt,
                                                  int2* __restrict__ ent) {
    int gid  = blockIdx.x * blockDim.x + threadIdx.x;
    int e    = gid >> 6, lane = gid & 63;
    int i = ind[2 * e], j = ind[2 * e + 1];
    float ski = sk[i * DD + lane], skj = sk[j * DD + lane];
    float d = ski * skj;
    #pragma unroll
    for (int off = 32; off; off >>= 1) d += __shfl_xor(d, off, 64);   // Gram
    if (lane == 0) {
        float Wij = 0.5f * (W[(size_t)i * NN + j] + W[(size_t)j * NN + i]);
        float gi = g[i], gj = g[j];
        float invKH = 1.f / kH[0];
        atomicAdd(&fH[i], d * Wij * gj * invKH);
        atomicAdd(&fH[j], d * Wij * gi * invKH);
        float cK = -gi * gj * Wij / kK[0];
        int2 pr;
        pr.y = __float_as_int(cK);
        int pi = atomicAdd(&cnt[i], 1);
        pr.x = j;  ent[i * CAP + pi] = pr;          // fK[i] += cK * sk[j]
        int pj = atomicAdd(&cnt[j], 1);
        pr.x = i;  ent[j * CAP + pj] = pr;          // fK[j] += cK * sk[i]
    }
}

// ---------------- K edges: polynomial coeff + adjacency build ----------------
__global__ __launch_bounds__(256) void k_edges_k(const float* __restrict__ sk,
                                                 const int* __restrict__ ind,
                                                 const float* __restrict__ coeffs,
                                                 int* __restrict__ cnt,
                                                 int2* __restrict__ ent) {
    int gid  = blockIdx.x * blockDim.x + threadIdx.x;
    int e    = gid >> 6, lane = gid & 63;
    int a = ind[2 * e], b = ind[2 * e + 1];
    float ska = sk[a * DD + lane], skb = sk[b * DD + lane];
    float s = ska * skb;
    #pragma unroll
    for (int off = 32; off; off >>= 1) s += __shfl_xor(s, off, 64);
    if (lane == 0) {
        float c0 = coeffs[0], c1 = coeffs[1], c2 = coeffs[2], c3 = coeffs[3];
        float dE = s * (c0 + s * (c1 + s * (c2 + s * c3)));  // c0 s + c1 s^2 + c2 s^3 + c3 s^4
        int2 pr;
        pr.y = __float_as_int(dE);
        int pa = atomicAdd(&cnt[a], 1);
        pr.x = b;  ent[a * CAP + pa] = pr;          // fK[a] += dE * sk[b]
        int pb = atomicAdd(&cnt[b], 1);
        pr.x = a;  ent[b * CAP + pb] = pr;          // fK[b] += dE * sk[a]
    }
}

// ---------------- gather + finalize: one wave per node ----------------
// fK accumulated in registers; outK = -f + sk*(sk.f) + sk @ (omega-omega^T)/2
__global__ __launch_bounds__(256) void k_gather_fin(const float* __restrict__ sk,
                                                    const int* __restrict__ cnt,
                                                    const int2* __restrict__ ent,
                                                    const float* __restrict__ omega,
                                                    float* __restrict__ outK) {
    __shared__ float A[DD * DD];    // antisymmetric part, 16 KB
    for (int t = threadIdx.x; t < DD * DD; t += 256) {
        int k = t >> 6, dcol = t & 63;
        A[t] = 0.5f * (omega[k * DD + dcol] - omega[dcol * DD + k]);
    }
    __syncthreads();
    int gid = blockIdx.x * blockDim.x + threadIdx.x;
    int row = gid >> 6, lane = gid & 63;
    const int2* __restrict__ el = ent + row * CAP;
    int m = cnt[row];
    float acc = 0.f;
    int full = m & ~63;
    for (int base = 0; base < full; base += 64) {
        int2 e = el[base + lane];                   // 64 entries staged in regs
        #pragma unroll 8
        for (int t = 0; t < 64; ++t) {
            int   other = __shfl(e.x, t, 64);
            float c     = __int_as_float(__shfl(e.y, t, 64));
            acc += c * sk[other * DD + lane];       // coalesced 256B gather
        }
    }
    int rem = m - full;
    {
        int2 e = (lane < rem) ? el[full + lane] : make_int2(0, 0);
        for (int t = 0; t < rem; ++t) {
            int   other = __shfl(e.x, t, 64);
            float c     = __int_as_float(__shfl(e.y, t, 64));
            acc += c * sk[other * DD + lane];
        }
    }
    // finalize
    float s = sk[row * DD + lane];
    float d = s * acc;
    #pragma unroll
    for (int off = 32; off; off >>= 1) d += __shfl_xor(d, off, 64);   // sk . f
    float accA = 0.f;
    #pragma unroll
    for (int k = 0; k < DD; ++k) {
        float skk = __shfl(s, k, 64);
        accA += skk * A[k * DD + lane];
    }
    outK[row * DD + lane] = -acc + s * d + accA;
}

extern "C" void kernel_launch(void* const* d_in, const int* in_sizes, int n_in,
                              void* d_out, int out_size, void* d_ws, size_t ws_size,
                              hipStream_t stream) {
    const float* H      = (const float*)d_in[0];
    const float* K      = (const float*)d_in[1];
    const float* W      = (const float*)d_in[2];
    const float* coeffs = (const float*)d_in[3];
    const float* omega  = (const float*)d_in[4];
    const int*   indK   = (const int*)d_in[5];
    const int*   indHK  = (const int*)d_in[6];
    const float* kK     = (const float*)d_in[7];
    const float* kH     = (const float*)d_in[8];

    float* fH    = (float*)d_out;            // N
    float* fKout = (float*)d_out + NN;       // N*D

    float* sk  = (float*)d_ws;                         // N*D floats
    float* g   = sk + (size_t)NN * DD;                 // N floats
    int*   cnt = (int*)(g + NN);                       // N ints
    int2*  ent = (int2*)(cnt + NN);                    // N*CAP int2 (16 MB)

    hipLaunchKernelGGL(k_prep_sk,  dim3(NN * DD / 256), dim3(256), 0, stream, K, sk);
    hipLaunchKernelGGL(k_prep_vec, dim3(NN / 256),      dim3(256), 0, stream, H, g, fH, cnt);
    hipLaunchKernelGGL(k_matvec,   dim3(NN / MV_ROWS),  dim3(MV_THREADS), 0, stream, W, g, fH);
    hipLaunchKernelGGL(k_edges_hk, dim3(NE / 4), dim3(256), 0, stream, W, sk, g, indHK, kH, kK, fH, cnt, ent);
    hipLaunchKernelGGL(k_edges_k,  dim3(NE / 4), dim3(256), 0, stream, sk, indK, coeffs, cnt, ent);
    hipLaunchKernelGGL(k_gather_fin, dim3(NN / 4), dim3(256), 0, stream, sk, cnt, ent, omega, fKout);
}